// Round 2
// baseline (415.042 us; speedup 1.0000x reference)
//
#include <hip/hip_runtime.h>

typedef __attribute__((ext_vector_type(8))) short short8;
typedef __attribute__((ext_vector_type(4))) float floatx4;

__device__ inline unsigned short f2bf(float f) {
  union { float f; unsigned int u; } c; c.f = f;
  unsigned int u = c.u;
  return (unsigned short)((u + 0x7fffu + ((u >> 16) & 1u)) >> 16);
}
__device__ inline float bf2f(unsigned short h) {
  union { unsigned int u; float f; } c; c.u = ((unsigned int)h) << 16;
  return c.f;
}

// ---------------- kW: fp32 -> (bf16-hi, bf16-lo) weight planes ----------------
__global__ __launch_bounds__(256) void kW(const float* __restrict__ w1,
                                          const float* __restrict__ w2,
                                          const float* __restrict__ w3,
                                          unsigned short* __restrict__ w1h,
                                          unsigned short* __restrict__ w1l,
                                          unsigned short* __restrict__ w2h,
                                          unsigned short* __restrict__ w2l,
                                          unsigned short* __restrict__ w3h,
                                          unsigned short* __restrict__ w3l) {
  int i = blockIdx.x * 256 + threadIdx.x;
  if (i < 202752) {
    float v = w1[i]; unsigned short hi = f2bf(v);
    w1h[i] = hi; w1l[i] = f2bf(v - bf2f(hi));
  } else if (i < 211968) {
    int k = i - 202752;
    float v = w2[k]; unsigned short hi = f2bf(v);
    w2h[k] = hi; w2l[k] = f2bf(v - bf2f(hi));
  } else if (i < 221184) {
    int k = i - 211968;
    float v = w3[k]; unsigned short hi = f2bf(v);
    w3h[k] = hi; w3l[k] = f2bf(v - bf2f(hi));
  }
}

// ---------------- kDesc: scrambled-unfold descriptors -> desc [12544, 2112] hi/lo bf16 ----
// TRUE geometry (reference's stack(axis=3) quirk): for output pos (h',w'), tap(k1,k2) =
//   x[row = (k2*56+h')/3 + k1 - 1, col = w' + (k2*56+h')%3 - 1]  (zero pad)
// block = (b, h', g): 4*56*16 = 3584 blocks, 256 threads
__global__ __launch_bounds__(256) void kDesc(const float* __restrict__ x,
                                             unsigned short* __restrict__ descH,
                                             unsigned short* __restrict__ descL,
                                             int uselo) {
  int bid = blockIdx.x;
  int g = bid & 15;
  int h = (bid >> 4) % 56;
  int b = bid / 896;
  __shared__ float xb[9 * 16 * 58];  // [((k2*3+k1)*16 + i)*58 + wc], wc -> w = wc-1
  int R2[3], j2[3];
#pragma unroll
  for (int k2 = 0; k2 < 3; ++k2) { int q = k2 * 56 + h; R2[k2] = q / 3; j2[k2] = q % 3; }
  int t = threadIdx.x;
  for (int idx = t; idx < 8352; idx += 256) {
    int wc = idx % 58;
    int i = (idx / 58) & 15;
    int kk = idx / 928;           // k2*3+k1
    int k2 = kk / 3, k1 = kk % 3;
    int gr = R2[k2] + k1 - 1, wr = wc - 1;
    float v = 0.f;
    if (gr >= 0 && gr < 56 && wr >= 0 && wr < 56)
      v = x[(((long)b * 256 + g * 16 + i) * 56 + gr) * 56 + wr];
    xb[idx] = v;
  }
  __syncthreads();
  long mrow0 = ((long)(b * 56 + h)) * 56;
  for (int e = t; e < 7392; e += 256) {
    int p = e / 132, dl = e % 132;
    float v; int dglob;
    if (dl < 36) {                       // x1: max over a2; idx a3*9 + k1*3 + k2
      int a3 = dl / 9, rem = dl % 9, k1 = rem / 3, k2 = rem % 3;
      int base = (k2 * 3 + k1) * 16, col = p + j2[k2];
      float a0 = xb[(base + a3) * 58 + col];
      float a1 = xb[(base + 4 + a3) * 58 + col];
      float a2v = xb[(base + 8 + a3) * 58 + col];
      float a3v = xb[(base + 12 + a3) * 58 + col];
      v = fmaxf(fmaxf(a0, a1), fmaxf(a2v, a3v));
      dglob = g * 36 + dl;
    } else if (dl < 84) {                // x2: max over k1; idx gc*3 + k2
      int u = dl - 36, gc = u / 3, k2 = u % 3;
      int col = p + j2[k2];
      float a0 = xb[((k2 * 3 + 0) * 16 + gc) * 58 + col];
      float a1 = xb[((k2 * 3 + 1) * 16 + gc) * 58 + col];
      float a2v = xb[((k2 * 3 + 2) * 16 + gc) * 58 + col];
      v = fmaxf(fmaxf(a0, a1), a2v);
      dglob = 576 + g * 48 + u;
    } else {                             // x3: max over k2; idx gc*3 + k1
      int u = dl - 84, gc = u / 3, k1 = u % 3;
      float a0 = xb[((0 * 3 + k1) * 16 + gc) * 58 + p + j2[0]];
      float a1 = xb[((1 * 3 + k1) * 16 + gc) * 58 + p + j2[1]];
      float a2v = xb[((2 * 3 + k1) * 16 + gc) * 58 + p + j2[2]];
      v = fmaxf(fmaxf(a0, a1), a2v);
      dglob = 1344 + g * 48 + u;
    }
    unsigned short hi = f2bf(v);
    long di = (mrow0 + p) * 2112 + dglob;
    descH[di] = hi;
    if (uselo) descL[di] = f2bf(v - bf2f(hi));
  }
}

// ---------------- kGemm: desc x w1 (split bf16) -> BN/ReLU -> (w2,w3 split) -> softmax -> wt fp16
// 196 blocks x 256 threads (4 waves); GEMM-1 all-register (A,B frags straight from global)
__global__ __launch_bounds__(256) void kGemm(
    const unsigned short* __restrict__ descH, const unsigned short* __restrict__ descL,
    const unsigned short* __restrict__ w1h, const unsigned short* __restrict__ w1l,
    const unsigned short* __restrict__ w2h, const unsigned short* __restrict__ w2l,
    const unsigned short* __restrict__ w3h, const unsigned short* __restrict__ w3l,
    const float* __restrict__ gamma, const float* __restrict__ beta,
    const float* __restrict__ mean, const float* __restrict__ var,
    const float* __restrict__ b2, const float* __restrict__ b3,
    _Float16* __restrict__ wtg, int uselo) {
  __shared__ __align__(16) char smem[49152];
  unsigned short* ytH = (unsigned short*)smem;            // 64*104 bf16 (y hi)
  unsigned short* ytL = (unsigned short*)(smem + 13312);  // 64*104 bf16 (y lo)
  float* wal = (float*)smem;                              // phase3: 64*96 f32
  float* wbl = (float*)(smem + 24576);                    // phase3: 64*96 f32
  __shared__ float invv[96], biasv[96];

  const int t = threadIdx.x;
  const int wv = t >> 6, lane = t & 63, quad = lane >> 4, lr = lane & 15;
  const long mblk = (long)blockIdx.x * 64;

  if (t < 96) {
    float iv = gamma[t] * rsqrtf(var[t] + 1e-5f);
    invv[t] = iv; biasv[t] = beta[t] - mean[t] * iv;
  }

  const long abase = (mblk + wv * 16 + lr) * 2112 + quad * 8;
  const int wb1 = lr * 2112 + quad * 8;   // + j*33792 + kt*32

  floatx4 zero4 = {0.f, 0.f, 0.f, 0.f};
  floatx4 acc[6];
#pragma unroll
  for (int j = 0; j < 6; ++j) acc[j] = zero4;

  short8 cah, cal, cbh[6], cbl[6];
  cah = *(const short8*)(descH + abase);
  if (uselo) cal = *(const short8*)(descL + abase);
#pragma unroll
  for (int j = 0; j < 6; ++j) {
    cbh[j] = *(const short8*)(w1h + wb1 + j * 33792);
    cbl[j] = *(const short8*)(w1l + wb1 + j * 33792);
  }

  for (int kt = 0; kt < 66; ++kt) {
    short8 nah, nal, nbh[6], nbl[6];
    if (kt < 65) {
      int nx = (kt + 1) * 32;
      nah = *(const short8*)(descH + abase + nx);
      if (uselo) nal = *(const short8*)(descL + abase + nx);
#pragma unroll
      for (int j = 0; j < 6; ++j) {
        nbh[j] = *(const short8*)(w1h + wb1 + j * 33792 + nx);
        nbl[j] = *(const short8*)(w1l + wb1 + j * 33792 + nx);
      }
    }
#pragma unroll
    for (int j = 0; j < 6; ++j) {
      acc[j] = __builtin_amdgcn_mfma_f32_16x16x32_bf16(cah, cbh[j], acc[j], 0, 0, 0);
      acc[j] = __builtin_amdgcn_mfma_f32_16x16x32_bf16(cah, cbl[j], acc[j], 0, 0, 0);
    }
    if (uselo) {
#pragma unroll
      for (int j = 0; j < 6; ++j)
        acc[j] = __builtin_amdgcn_mfma_f32_16x16x32_bf16(cal, cbh[j], acc[j], 0, 0, 0);
    }
    if (kt < 65) {
      cah = nah;
      if (uselo) cal = nal;
#pragma unroll
      for (int j = 0; j < 6; ++j) { cbh[j] = nbh[j]; cbl[j] = nbl[j]; }
    }
  }

  __syncthreads();  // invv visible; smem first use
  // BN + ReLU -> y hi/lo bf16 tiles
#pragma unroll
  for (int j = 0; j < 6; ++j) {
    int n = j * 16 + lr;
    float iv = invv[n], bv = biasv[n];
#pragma unroll
    for (int r = 0; r < 4; ++r) {
      int m = wv * 16 + quad * 4 + r;
      float y = fmaxf(acc[j][r] * iv + bv, 0.f);
      unsigned short hi = f2bf(y);
      ytH[m * 104 + n] = hi;
      ytL[m * 104 + n] = f2bf(y - bf2f(hi));
    }
  }
  __syncthreads();

  floatx4 acc2a[6], acc2b[6];
#pragma unroll
  for (int j = 0; j < 6; ++j) { acc2a[j] = zero4; acc2b[j] = zero4; }
#pragma unroll
  for (int ks = 0; ks < 3; ++ks) {
    short8 afh = *(const short8*)(ytH + (wv * 16 + lr) * 104 + ks * 32 + quad * 8);
    short8 afl = *(const short8*)(ytL + (wv * 16 + lr) * 104 + ks * 32 + quad * 8);
#pragma unroll
    for (int j = 0; j < 6; ++j) {
      int wo = j * 1536 + lr * 96 + ks * 32 + quad * 8;
      short8 bh2 = *(const short8*)(w2h + wo);
      short8 bl2 = *(const short8*)(w2l + wo);
      short8 bh3 = *(const short8*)(w3h + wo);
      short8 bl3 = *(const short8*)(w3l + wo);
      acc2a[j] = __builtin_amdgcn_mfma_f32_16x16x32_bf16(afh, bh2, acc2a[j], 0, 0, 0);
      acc2a[j] = __builtin_amdgcn_mfma_f32_16x16x32_bf16(afl, bh2, acc2a[j], 0, 0, 0);
      acc2a[j] = __builtin_amdgcn_mfma_f32_16x16x32_bf16(afh, bl2, acc2a[j], 0, 0, 0);
      acc2b[j] = __builtin_amdgcn_mfma_f32_16x16x32_bf16(afh, bh3, acc2b[j], 0, 0, 0);
      acc2b[j] = __builtin_amdgcn_mfma_f32_16x16x32_bf16(afl, bh3, acc2b[j], 0, 0, 0);
      acc2b[j] = __builtin_amdgcn_mfma_f32_16x16x32_bf16(afh, bl3, acc2b[j], 0, 0, 0);
    }
  }
  __syncthreads();  // ytH/ytL dead; reuse smem as wal/wbl

#pragma unroll
  for (int j = 0; j < 6; ++j) {
    int n = j * 16 + lr;
    float bb2 = b2[n], bb3 = b3[n];
#pragma unroll
    for (int r = 0; r < 4; ++r) {
      int m = wv * 16 + quad * 4 + r;
      wal[m * 96 + n] = acc2a[j][r] + bb2;
      wbl[m * 96 + n] = acc2b[j][r] + bb3;
    }
  }
  __syncthreads();

  // softmax over 9 logits la[k1]*lb[k2] per (m, g, ns1, ns2); /9 mean folded; fp16 out
  for (int it = 0; it < 16; ++it) {
    int u = t + it * 256;
    int m = u >> 6, rest = u & 63;
    int g = rest >> 2, ns = rest & 3;
    int ns1 = ns >> 1, ns2 = ns & 1;
    float la[3], lb[3];
#pragma unroll
    for (int k = 0; k < 3; ++k) {
      la[k] = wal[m * 96 + (g * 3 + k) * 2 + ns1];
      lb[k] = wbl[m * 96 + (g * 3 + k) * 2 + ns2];
    }
    float lg[9], mx = -1e30f;
#pragma unroll
    for (int k1 = 0; k1 < 3; ++k1)
#pragma unroll
      for (int k2 = 0; k2 < 3; ++k2) {
        float v = la[k1] * lb[k2];
        lg[k1 * 3 + k2] = v;
        mx = v > mx ? v : mx;
      }
    float s = 0.f;
#pragma unroll
    for (int k = 0; k < 9; ++k) { lg[k] = __expf(lg[k] - mx); s += lg[k]; }
    float sc = 1.f / (9.f * s);
    _Float16* dst = wtg + (mblk + m) * 576 + g * 36 + ns * 9;
#pragma unroll
    for (int k = 0; k < 9; ++k) dst[k] = (_Float16)(lg[k] * sc);
  }
}

// ---------------- kApply: x + wt -> out (scrambled tap geometry, coalesced writes) ----
// block = (b, h', wh(2), cq(8)): 3584 blocks, 256 threads; 32 channels, 28 w-positions
__global__ __launch_bounds__(256) void kApply(const float* __restrict__ x,
                                              const _Float16* __restrict__ wt,
                                              float* __restrict__ out) {
  int bid = blockIdx.x;
  int cq = bid & 7;
  int wh = (bid >> 3) & 1;
  int h = (bid >> 4) % 56;
  int b = bid / 896;
  int wbase = wh * 28, cbase = cq * 32;

  __shared__ float xr[9 * 32 * 30];   // [((k2*3+k1)*32 + cl)*30 + wc]
  __shared__ float wtb[28 * 72];      // [p*72 + gp*36 + ns*9 + kk]
  __shared__ float ob[32 * 2 * 56];   // [(cl*2+ns1)*56 + wout]

  int R2[3], j2[3];
#pragma unroll
  for (int k2 = 0; k2 < 3; ++k2) { int q = k2 * 56 + h; R2[k2] = q / 3; j2[k2] = q % 3; }

  int t = threadIdx.x;
  for (int idx = t; idx < 8640; idx += 256) {
    int wc = idx % 30;
    int cl = (idx / 30) & 31;
    int kk = idx / 960;             // k2*3+k1
    int k2 = kk / 3, k1 = kk % 3;
    int gr = R2[k2] + k1 - 1, wr = wbase + wc - 1;
    float v = 0.f;
    if (gr >= 0 && gr < 56 && wr >= 0 && wr < 56)
      v = x[(((long)b * 256 + cbase + cl) * 56 + gr) * 56 + wr];
    xr[idx] = v;
  }
  long m0 = ((long)(b * 56 + h)) * 56 + wbase;
  for (int idx = t; idx < 2016; idx += 256) {
    int p = idx / 72, rem = idx % 72;
    wtb[idx] = (float)wt[(m0 + p) * 576 + cq * 72 + rem];
  }
  __syncthreads();

  int cl = (t & 127) >> 2;
  int ns = t & 3;
  int ns1 = ns >> 1, ns2 = ns & 1;
  int psel = t >> 7;
  int gp = cl >> 4;
  for (int it = 0; it < 14; ++it) {
    int p = it * 2 + psel;
    float accv = 0.f;
#pragma unroll
    for (int k1 = 0; k1 < 3; ++k1)
#pragma unroll
      for (int k2 = 0; k2 < 3; ++k2) {
        accv += xr[((k2 * 3 + k1) * 32 + cl) * 30 + p + j2[k2]] *
                wtb[p * 72 + gp * 36 + ns * 9 + k1 * 3 + k2];
      }
    ob[(cl * 2 + ns1) * 56 + p * 2 + ns2] = accv;
  }
  __syncthreads();

  for (int idx = t; idx < 3584; idx += 256) {
    int wo = idx % 56;
    int n1 = (idx / 56) & 1;
    int cli = idx / 112;
    out[(((long)b * 256 + cbase + cli) * 112 + (2 * h + n1)) * 112 + wh * 56 + wo] = ob[idx];
  }
}

extern "C" void kernel_launch(void* const* d_in, const int* in_sizes, int n_in,
                              void* d_out, int out_size, void* d_ws, size_t ws_size,
                              hipStream_t stream) {
  const float* x = (const float*)d_in[0];
  const float* w1 = (const float*)d_in[1];
  const float* gamma = (const float*)d_in[2];
  const float* beta = (const float*)d_in[3];
  const float* mean = (const float*)d_in[4];
  const float* var = (const float*)d_in[5];
  const float* w2 = (const float*)d_in[6];
  const float* b2 = (const float*)d_in[7];
  const float* w3 = (const float*)d_in[8];
  const float* b3 = (const float*)d_in[9];
  float* out = (float*)d_out;

  // workspace layout (bytes):
  //   weights hi/lo:          [0, 884736)
  //   wtg fp16:               [884736, 15335424)
  //   descH bf16:             [15335424, 68321280)
  //   descL bf16 (optional):  [68321280, 121307136)
  unsigned short* w1h = (unsigned short*)d_ws;
  unsigned short* w1l = w1h + 202752;
  unsigned short* w2h = w1l + 202752;
  unsigned short* w2l = w2h + 9216;
  unsigned short* w3h = w2l + 9216;
  unsigned short* w3l = w3h + 9216;
  _Float16* wtg = (_Float16*)((char*)d_ws + 884736);
  unsigned short* descH = (unsigned short*)((char*)d_ws + 15335424);
  unsigned short* descL = descH + 26492928;
  int uselo = (ws_size >= (size_t)121307136) ? 1 : 0;

  hipLaunchKernelGGL(kW, dim3(864), dim3(256), 0, stream,
                     w1, w2, w3, w1h, w1l, w2h, w2l, w3h, w3l);
  hipLaunchKernelGGL(kDesc, dim3(3584), dim3(256), 0, stream, x, descH, descL, uselo);
  hipLaunchKernelGGL(kGemm, dim3(196), dim3(256), 0, stream,
                     descH, descL, w1h, w1l, w2h, w2l, w3h, w3l,
                     gamma, beta, mean, var, b2, b3, wtg, uselo);
  hipLaunchKernelGGL(kApply, dim3(3584), dim3(256), 0, stream, x, wtg, out);
}